// Round 16
// baseline (201.888 us; speedup 1.0000x reference)
//
#include <hip/hip_runtime.h>
#include <hip/hip_bf16.h>

// Problem constants (B=4, C=256, H=W=64, heads=4)
#define NPOS   4096          // H*W
#define TOTP   16384         // B*NPOS
#define C      256
#define DH     64

typedef unsigned short ushort_t;
typedef __attribute__((ext_vector_type(8))) short short8;   // 8 bf16 (4 VGPRs) MFMA A/B frag
typedef __attribute__((ext_vector_type(4))) float f32x4;    // MFMA C/D frag

__device__ __forceinline__ f32x4 mfma16(short8 a, short8 b, f32x4 c) {
  return __builtin_amdgcn_mfma_f32_16x16x32_bf16(a, b, c, 0, 0, 0);
}

// fp32 -> bf16 bits, round-to-nearest-even (inputs finite)
__device__ __forceinline__ ushort_t f2bf(float f) {
  union { float f; unsigned int u; } v;
  v.f = f;
  unsigned int r = v.u + 0x7FFFu + ((v.u >> 16) & 1u);
  return (ushort_t)(r >> 16);
}

// pack two fp32 -> u32 of 2x bf16 (RNE) via the official conversion intrinsic;
// hipcc lowers the pair to v_cvt_pk_bf16_f32 (1 op vs ~12 for bit-twiddle).
__device__ __forceinline__ unsigned int pack_bf16x2(float lo, float hi) {
  __hip_bfloat162 h = __float22bfloat162_rn(float2{lo, hi});
  union { __hip_bfloat162 h; unsigned int u; } v;
  v.h = h;
  return v.u;
}

// raw v_exp_f32: D = 2^S0, single trans op. Inputs bounded <= +8 by defer-max;
// large-negative inputs flush to 0 (desired for softmax).
__device__ __forceinline__ float fast_exp2(float x) {
  float r;
  asm("v_exp_f32 %0, %1" : "=v"(r) : "v"(x));
  return r;
}

// ---------------------------------------------------------------------------
// Pack weights to bf16. Q rows (o<256) of w_qkv get the attention scale AND
// log2(e) folded in: softmax then uses one bare v_exp_f32 per P element.
__global__ __launch_bounds__(256) void pack_w(const float* __restrict__ wq,
                                              const float* __restrict__ wp,
                                              ushort_t* __restrict__ wqb,
                                              ushort_t* __restrict__ wpb) {
  int idx = blockIdx.x * 256 + threadIdx.x;
  if (idx < 49152) {                       // w_qkv: 768*256 = 196608 = 49152*4
    float4 v = *(const float4*)(wq + (size_t)idx * 4);
    // Q rows: 0.125 * log2(e) = 0.18033688011
    float sc = (idx * 4 < 65536) ? 0.18033688f : 1.0f;
    ushort_t* d = wqb + (size_t)idx * 4;
    unsigned long long pk =
        (unsigned long long)f2bf(v.x * sc) |
        ((unsigned long long)f2bf(v.y * sc) << 16) |
        ((unsigned long long)f2bf(v.z * sc) << 32) |
        ((unsigned long long)f2bf(v.w * sc) << 48);
    *(unsigned long long*)d = pk;
  } else {                                 // w_proj: 256*256 = 65536 = 16384*4
    int j = idx - 49152;
    float4 v = *(const float4*)(wp + (size_t)j * 4);
    ushort_t* d = wpb + (size_t)j * 4;
    unsigned long long pk =
        (unsigned long long)f2bf(v.x) |
        ((unsigned long long)f2bf(v.y) << 16) |
        ((unsigned long long)f2bf(v.z) << 32) |
        ((unsigned long long)f2bf(v.w) << 48);
    *(unsigned long long*)d = pk;
  }
}

// ---------------------------------------------------------------------------
// x [b][c][n] fp32  ->  xT [b*4096+n][c] bf16   (LDS tile transpose)
__global__ __launch_bounds__(256) void transpose_pack(const float* __restrict__ x,
                                                      ushort_t* __restrict__ xT) {
  __shared__ ushort_t tile[64][68];
  int nb = blockIdx.x * 64, cb = blockIdx.y * 64, b = blockIdx.z;
  int tr = threadIdx.x >> 4;            // 0..15
  int tc = (threadIdx.x & 15) * 4;      // 0..60
  const float* src = x + ((size_t)b * C + cb) * NPOS + nb;
#pragma unroll
  for (int it = 0; it < 4; ++it) {
    int c = tr + it * 16;
    float4 v = *(const float4*)(src + (size_t)c * NPOS + tc);
    tile[c][tc + 0] = f2bf(v.x);
    tile[c][tc + 1] = f2bf(v.y);
    tile[c][tc + 2] = f2bf(v.z);
    tile[c][tc + 3] = f2bf(v.w);
  }
  __syncthreads();
  ushort_t* dst = xT + ((size_t)b * NPOS + nb) * C + cb;
#pragma unroll
  for (int it = 0; it < 4; ++it) {
    int n = tr + it * 16;
    unsigned long long pk =
        (unsigned long long)tile[tc + 0][n] |
        ((unsigned long long)tile[tc + 1][n] << 16) |
        ((unsigned long long)tile[tc + 2][n] << 32) |
        ((unsigned long long)tile[tc + 3][n] << 48);
    *(unsigned long long*)(dst + (size_t)n * C + tc) = pk;
  }
}

// ---------------------------------------------------------------------------
// QK GEMM: qk[p][o] = sum_c xT[p][c] * Wq[o][c],  o in [0,512)  (Q pre-scaled)
// wave = 32 p x 64 o. grid (128 p-tiles, 8 o-tiles).
__global__ __launch_bounds__(256) void gemm_qk(const ushort_t* __restrict__ xT,
                                               const ushort_t* __restrict__ Wq,
                                               ushort_t* __restrict__ qk) {
  int w = threadIdx.x >> 6, l = threadIdx.x & 63;
  int lr = l & 15, lg = l >> 4;
  int mbase = blockIdx.x * 128 + w * 32;
  int nbase = blockIdx.y * 64;
  f32x4 acc[2][4] = {};
#pragma unroll
  for (int kk = 0; kk < 8; ++kk) {
    short8 a0 = *(const short8*)(xT + (size_t)(mbase + lr) * C + kk * 32 + lg * 8);
    short8 a1 = *(const short8*)(xT + (size_t)(mbase + 16 + lr) * C + kk * 32 + lg * 8);
#pragma unroll
    for (int t = 0; t < 4; ++t) {
      short8 b = *(const short8*)(Wq + (size_t)(nbase + t * 16 + lr) * C + kk * 32 + lg * 8);
      acc[0][t] = mfma16(a0, b, acc[0][t]);
      acc[1][t] = mfma16(a1, b, acc[1][t]);
    }
  }
#pragma unroll
  for (int qq = 0; qq < 2; ++qq)
#pragma unroll
    for (int t = 0; t < 4; ++t)
#pragma unroll
      for (int i = 0; i < 4; ++i)
        qk[(size_t)(mbase + qq * 16 + lg * 4 + i) * 512 + nbase + t * 16 + lr] =
            f2bf(acc[qq][t][i]);
}

// ---------------------------------------------------------------------------
// V GEMM with swapped roles: vT[b*256 + ov][n] = sum_c Wq[512+ov][c]*xT[p][c]
// Output is V already transposed (d-major). wave = 32 ov x 64 p.
__global__ __launch_bounds__(256) void gemm_v(const ushort_t* __restrict__ xT,
                                              const ushort_t* __restrict__ Wq,
                                              ushort_t* __restrict__ vT) {
  int w = threadIdx.x >> 6, l = threadIdx.x & 63;
  int lr = l & 15, lg = l >> 4;
  int obase = blockIdx.y * 128 + w * 32;       // 0..255 (V channel)
  int pbase = blockIdx.x * 64;
  f32x4 acc[2][4] = {};
#pragma unroll
  for (int kk = 0; kk < 8; ++kk) {
    short8 a0 = *(const short8*)(Wq + (size_t)(512 + obase + lr) * C + kk * 32 + lg * 8);
    short8 a1 = *(const short8*)(Wq + (size_t)(512 + obase + 16 + lr) * C + kk * 32 + lg * 8);
#pragma unroll
    for (int t = 0; t < 4; ++t) {
      short8 b = *(const short8*)(xT + (size_t)(pbase + t * 16 + lr) * C + kk * 32 + lg * 8);
      acc[0][t] = mfma16(a0, b, acc[0][t]);
      acc[1][t] = mfma16(a1, b, acc[1][t]);
    }
  }
#pragma unroll
  for (int qq = 0; qq < 2; ++qq)
#pragma unroll
    for (int i = 0; i < 4; ++i) {
      int ov = obase + qq * 16 + lg * 4 + i;
#pragma unroll
      for (int t = 0; t < 4; ++t) {
        int p = pbase + t * 16 + lr;
        vT[((size_t)((p >> 12) * 256 + ov)) * NPOS + (p & 4095)] = f2bf(acc[qq][t][i]);
      }
    }
}

// ---------------------------------------------------------------------------
// Flash attention. Block = 4 waves x 32 q-rows = 128 q. grid (32 qtiles, 16 bh).
// Round-12 machinery, K/V SINGLE-buffered: LDS 48 -> 32 KB. With plain
// __launch_bounds__(256) the VGPR count stays ~100 (<=128 threshold), so HW
// occupancy rises to 4 blocks/CU = 16 waves/CU. (Round 14 tested this with
// __launch_bounds__(256,4), which CAPPED VGPRs at 64 -> scratch spill, 5x —
// that run tested the register cap, not the occupancy hypothesis.)
// Cost: 2 barriers/iter (drain reads -> write -> publish).
// If this regresses vs 135.5 us, revert to the round-12 double-buffer config.
__global__ __launch_bounds__(256) void attn_kernel(const ushort_t* __restrict__ qk,
                                                   const ushort_t* __restrict__ vT,
                                                   ushort_t* __restrict__ ao) {
  __shared__ ushort_t Ks[64][64];         // [key][d], swizzled rows (8 KB)
  __shared__ ushort_t Vs[64][64];         // [d][key], swizzled rows (8 KB)
  __shared__ ushort_t Pw[4][2048];        // per-wave P [32 q][64 key] (16 KB)

  int tid = threadIdx.x;                  // 0..255
  int w = tid >> 6, l = tid & 63;
  int lr = l & 15, lg = l >> 4;

  int bh = blockIdx.y;
  int qtile = blockIdx.x;                 // 0..31
  int b = bh >> 2, h = bh & 3;
  size_t bbase = (size_t)b * NPOS;
  int qbase = qtile * 128 + w * 32;       // this wave's 32 q-rows

  const ushort_t* qkb = qk + bbase * 512;
  const ushort_t* vTb = vT + ((size_t)(b * 256 + h * DH)) * NPOS;

  // ---- staging setup: thread handles chunks c = tid + j*256, j=0..1 ----
  // chunk c: row = c>>3 (key for K, d for V), 16B slot = c&7.
  const ushort_t* ksrc[2];
  const ushort_t* vsrc[2];
  ushort_t* kdst[2];
  ushort_t* vdst[2];
#pragma unroll
  for (int j = 0; j < 2; ++j) {
    int c = j * 256 + tid;
    int row = c >> 3, slot = c & 7;
    ksrc[j] = qkb + (size_t)row * 512 + 256 + h * DH + slot * 8;   // tile 0
    vsrc[j] = vTb + (size_t)row * NPOS + slot * 8;                 // tile 0
    kdst[j] = &Ks[row][((slot * 16) ^ (((row >> 2) & 7) << 4)) >> 1];
    vdst[j] = &Vs[row][((slot * 16) ^ ((row & 7) << 4)) >> 1];
  }
  short8 gk[2], gv[2];
#pragma unroll
  for (int j = 0; j < 2; ++j) {           // prologue: load tile 0
    gk[j] = *(const short8*)ksrc[j];
    gv[j] = *(const short8*)vsrc[j];
  }

  // ---- Q fragments hoisted (scale + log2e pre-folded into W_q) ----
  short8 aq[2][2];
#pragma unroll
  for (int qq = 0; qq < 2; ++qq)
#pragma unroll
    for (int ks = 0; ks < 2; ++ks)
      aq[qq][ks] = *(const short8*)(qkb + (size_t)(qbase + qq * 16 + lr) * 512 +
                                    h * DH + ks * 32 + lg * 8);

  f32x4 o[2][4] = {};
  float mi[2][4] = {{-1e30f, -1e30f, -1e30f, -1e30f}, {-1e30f, -1e30f, -1e30f, -1e30f}};
  float li[2][4] = {};                    // per-lane partial row sums

  for (int kt = 0; kt < 64; ++kt) {
    // ---- drain: all waves' reads of the previous tile must finish ----
    __syncthreads();
    // ---- write phase: regs (tile kt) -> LDS ----
#pragma unroll
    for (int j = 0; j < 2; ++j) {
      *(short8*)kdst[j] = gk[j];
      *(short8*)vdst[j] = gv[j];
    }
    __syncthreads();

    // ---- issue next tile's loads (latency hides under compute) ----
    if (kt < 63) {
#pragma unroll
      for (int j = 0; j < 2; ++j) {
        ksrc[j] += 64 * 512;
        vsrc[j] += 64;
        gk[j] = *(const short8*)ksrc[j];
        gv[j] = *(const short8*)vsrc[j];
      }
    }

    // ---- S' = Q K^T (log2e-scaled; keys permuted: frag t col lr = key lr*4+t)
    f32x4 s[2][4] = {};
#pragma unroll
    for (int ks = 0; ks < 2; ++ks) {
      short8 bk[4];
#pragma unroll
      for (int t = 0; t < 4; ++t) {
        int row = lr * 4 + t;             // row>>2 == lr
        int colb = (ks * 64 + lg * 16) ^ ((lr & 7) << 4);
        bk[t] = *(const short8*)&Ks[row][colb >> 1];
      }
#pragma unroll
      for (int qq = 0; qq < 2; ++qq)
#pragma unroll
        for (int t = 0; t < 4; ++t)
          s[qq][t] = mfma16(aq[qq][ks], bk[t], s[qq][t]);
    }

    // ---- online softmax (exp2 domain) with defer-max ----
    float m4[2][4];
    bool bad = false;
#pragma unroll
    for (int qq = 0; qq < 2; ++qq)
#pragma unroll
      for (int i = 0; i < 4; ++i) {
        m4[qq][i] = fmaxf(fmaxf(s[qq][0][i], s[qq][1][i]),
                          fmaxf(s[qq][2][i], s[qq][3][i]));
        bad = bad || (m4[qq][i] > mi[qq][i] + 8.0f);
      }

    if (__any(bad)) {
      // slow path: full online-softmax rescale (rare after first tiles)
#pragma unroll
      for (int qq = 0; qq < 2; ++qq)
#pragma unroll
        for (int i = 0; i < 4; ++i) {
          float mx = m4[qq][i];
#pragma unroll
          for (int msk = 1; msk <= 8; msk <<= 1) mx = fmaxf(mx, __shfl_xor(mx, msk, 64));
          float mnew = fmaxf(mi[qq][i], mx);
          float corr = fast_exp2(mi[qq][i] - mnew);
          float p0 = fast_exp2(s[qq][0][i] - mnew);
          float p1 = fast_exp2(s[qq][1][i] - mnew);
          float p2 = fast_exp2(s[qq][2][i] - mnew);
          float p3 = fast_exp2(s[qq][3][i] - mnew);
          li[qq][i] = li[qq][i] * corr + ((p0 + p1) + (p2 + p3));
          mi[qq][i] = mnew;
#pragma unroll
          for (int t = 0; t < 4; ++t) o[qq][t][i] *= corr;
          int r = qq * 16 + lg * 4 + i;
          uint2 pr;
          pr.x = pack_bf16x2(p0, p1);
          pr.y = pack_bf16x2(p2, p3);
          *(uint2*)&Pw[w][r * 64 + ((lr * 4) ^ ((r & 7) << 3))] = pr;
        }
    } else {
      // fast path: stale max, no cross-lane ops, no rescale
#pragma unroll
      for (int qq = 0; qq < 2; ++qq)
#pragma unroll
        for (int i = 0; i < 4; ++i) {
          float m = mi[qq][i];
          float p0 = fast_exp2(s[qq][0][i] - m);
          float p1 = fast_exp2(s[qq][1][i] - m);
          float p2 = fast_exp2(s[qq][2][i] - m);
          float p3 = fast_exp2(s[qq][3][i] - m);
          li[qq][i] += (p0 + p1) + (p2 + p3);
          int r = qq * 16 + lg * 4 + i;
          uint2 pr;
          pr.x = pack_bf16x2(p0, p1);
          pr.y = pack_bf16x2(p2, p3);
          *(uint2*)&Pw[w][r * 64 + ((lr * 4) ^ ((r & 7) << 3))] = pr;
        }
    }

    // ---- O += P V ----
#pragma unroll
    for (int kk = 0; kk < 2; ++kk) {
      short8 bv[4];
#pragma unroll
      for (int t = 0; t < 4; ++t) {
        int row = t * 16 + lr;
        int colb = (kk * 64 + lg * 16) ^ ((row & 7) << 4);
        bv[t] = *(const short8*)&Vs[row][colb >> 1];
      }
#pragma unroll
      for (int qq = 0; qq < 2; ++qq) {
        int r = qq * 16 + lr;
        short8 ap = *(const short8*)&Pw[w][r * 64 + ((kk * 32 + lg * 8) ^ ((r & 7) << 3))];
#pragma unroll
        for (int t = 0; t < 4; ++t) o[qq][t] = mfma16(ap, bv[t], o[qq][t]);
      }
    }
  }

  // ---- reduce per-lane li across the 16 lr-lanes of each row group ----
#pragma unroll
  for (int qq = 0; qq < 2; ++qq)
#pragma unroll
    for (int i = 0; i < 4; ++i) {
      float rs = li[qq][i];
#pragma unroll
      for (int msk = 1; msk <= 8; msk <<= 1) rs += __shfl_xor(rs, msk, 64);
      li[qq][i] = rs;
    }

  // ---- epilogue: ao[p][h*64+d] = O/li ----
#pragma unroll
  for (int qq = 0; qq < 2; ++qq)
#pragma unroll
    for (int i = 0; i < 4; ++i) {
      float inv = 1.0f / li[qq][i];
      size_t p = bbase + qbase + qq * 16 + lg * 4 + i;
#pragma unroll
      for (int t = 0; t < 4; ++t)
        ao[p * C + h * DH + t * 16 + lr] = f2bf(o[qq][t][i] * inv);
    }
}

// ---------------------------------------------------------------------------
// Proj GEMM: out[b][o][n] = sum_c Wp[o][c]*ao[p][c] + bias[o]
// wave = 32 o x 64 p. grid (256 p-tiles, 2 o-tiles). fp32 stores to [o][n].
__global__ __launch_bounds__(256) void gemm_proj(const ushort_t* __restrict__ ao,
                                                 const ushort_t* __restrict__ Wp,
                                                 const float* __restrict__ bias,
                                                 float* __restrict__ out) {
  int w = threadIdx.x >> 6, l = threadIdx.x & 63;
  int lr = l & 15, lg = l >> 4;
  int obase = blockIdx.y * 128 + w * 32;
  int pbase = blockIdx.x * 64;
  f32x4 acc[2][4] = {};
#pragma unroll
  for (int kk = 0; kk < 8; ++kk) {
    short8 a0 = *(const short8*)(Wp + (size_t)(obase + lr) * C + kk * 32 + lg * 8);
    short8 a1 = *(const short8*)(Wp + (size_t)(obase + 16 + lr) * C + kk * 32 + lg * 8);
#pragma unroll
    for (int t = 0; t < 4; ++t) {
      short8 b = *(const short8*)(ao + (size_t)(pbase + t * 16 + lr) * C + kk * 32 + lg * 8);
      acc[0][t] = mfma16(a0, b, acc[0][t]);
      acc[1][t] = mfma16(a1, b, acc[1][t]);
    }
  }
#pragma unroll
  for (int qq = 0; qq < 2; ++qq)
#pragma unroll
    for (int i = 0; i < 4; ++i) {
      int oc = obase + qq * 16 + lg * 4 + i;
      float bv = bias[oc];
#pragma unroll
      for (int t = 0; t < 4; ++t) {
        int p = pbase + t * 16 + lr;
        out[((size_t)(p >> 12) * C + oc) * NPOS + (p & 4095)] = acc[qq][t][i] + bv;
      }
    }
}

// ---------------------------------------------------------------------------
extern "C" void kernel_launch(void* const* d_in, const int* in_sizes, int n_in,
                              void* d_out, int out_size, void* d_ws, size_t ws_size,
                              hipStream_t stream) {
  const float* x      = (const float*)d_in[0];
  const float* w_qkv  = (const float*)d_in[1];
  const float* w_proj = (const float*)d_in[2];
  const float* b_proj = (const float*)d_in[3];
  float* out = (float*)d_out;

  char* ws = (char*)d_ws;
  ushort_t* xT  = (ushort_t*)(ws);                 // 16384*256*2  =  8,388,608
  ushort_t* wqb = (ushort_t*)(ws + 8388608);       // 768*256*2    =    393,216
  ushort_t* wpb = (ushort_t*)(ws + 8781824);       // 256*256*2    =    131,072
  ushort_t* qk  = (ushort_t*)(ws + 8912896);       // 16384*512*2  = 16,777,216
  ushort_t* vT  = (ushort_t*)(ws + 25690112);      // 4*256*4096*2 =  8,388,608
  ushort_t* ao  = (ushort_t*)(ws + 34078720);      // 16384*256*2  =  8,388,608
                                                   // total 42,467,328 bytes

  pack_w<<<256, 256, 0, stream>>>(w_qkv, w_proj, wqb, wpb);
  transpose_pack<<<dim3(64, 4, 4), 256, 0, stream>>>(x, xT);
  gemm_qk<<<dim3(128, 8), 256, 0, stream>>>(xT, wqb, qk);
  gemm_v<<<dim3(256, 2), 256, 0, stream>>>(xT, wqb, vT);
  attn_kernel<<<dim3(32, 16), 256, 0, stream>>>(qk, vT, ao);
  gemm_proj<<<dim3(256, 2), 256, 0, stream>>>(ao, wpb, b_proj, out);
}

// Round 17
// 179.581 us; speedup vs baseline: 1.1242x; 1.1242x over previous
//
#include <hip/hip_runtime.h>
#include <hip/hip_bf16.h>

// Problem constants (B=4, C=256, H=W=64, heads=4)
#define NPOS   4096          // H*W
#define TOTP   16384         // B*NPOS
#define C      256
#define DH     64

typedef unsigned short ushort_t;
typedef __attribute__((ext_vector_type(8))) short short8;   // 8 bf16 (4 VGPRs) MFMA A/B frag
typedef __attribute__((ext_vector_type(4))) float f32x4;    // MFMA C/D frag

__device__ __forceinline__ f32x4 mfma16(short8 a, short8 b, f32x4 c) {
  return __builtin_amdgcn_mfma_f32_16x16x32_bf16(a, b, c, 0, 0, 0);
}

// fp32 -> bf16 bits, round-to-nearest-even (inputs finite)
__device__ __forceinline__ ushort_t f2bf(float f) {
  union { float f; unsigned int u; } v;
  v.f = f;
  unsigned int r = v.u + 0x7FFFu + ((v.u >> 16) & 1u);
  return (ushort_t)(r >> 16);
}

// pack two fp32 -> u32 of 2x bf16 (RNE) via the official conversion intrinsic;
// hipcc lowers the pair to v_cvt_pk_bf16_f32 (1 op vs ~12 for bit-twiddle).
__device__ __forceinline__ unsigned int pack_bf16x2(float lo, float hi) {
  __hip_bfloat162 h = __float22bfloat162_rn(float2{lo, hi});
  union { __hip_bfloat162 h; unsigned int u; } v;
  v.h = h;
  return v.u;
}

// raw v_exp_f32: D = 2^S0, single trans op. Inputs bounded <= +8 by defer-max;
// large-negative inputs flush to 0 (desired for softmax).
__device__ __forceinline__ float fast_exp2(float x) {
  float r;
  asm("v_exp_f32 %0, %1" : "=v"(r) : "v"(x));
  return r;
}

// ---------------------------------------------------------------------------
// Pack weights to bf16. Q rows (o<256) of w_qkv get the attention scale AND
// log2(e) folded in: softmax then uses one bare v_exp_f32 per P element.
__global__ __launch_bounds__(256) void pack_w(const float* __restrict__ wq,
                                              const float* __restrict__ wp,
                                              ushort_t* __restrict__ wqb,
                                              ushort_t* __restrict__ wpb) {
  int idx = blockIdx.x * 256 + threadIdx.x;
  if (idx < 49152) {                       // w_qkv: 768*256 = 196608 = 49152*4
    float4 v = *(const float4*)(wq + (size_t)idx * 4);
    // Q rows: 0.125 * log2(e) = 0.18033688011
    float sc = (idx * 4 < 65536) ? 0.18033688f : 1.0f;
    ushort_t* d = wqb + (size_t)idx * 4;
    unsigned long long pk =
        (unsigned long long)f2bf(v.x * sc) |
        ((unsigned long long)f2bf(v.y * sc) << 16) |
        ((unsigned long long)f2bf(v.z * sc) << 32) |
        ((unsigned long long)f2bf(v.w * sc) << 48);
    *(unsigned long long*)d = pk;
  } else {                                 // w_proj: 256*256 = 65536 = 16384*4
    int j = idx - 49152;
    float4 v = *(const float4*)(wp + (size_t)j * 4);
    ushort_t* d = wpb + (size_t)j * 4;
    unsigned long long pk =
        (unsigned long long)f2bf(v.x) |
        ((unsigned long long)f2bf(v.y) << 16) |
        ((unsigned long long)f2bf(v.z) << 32) |
        ((unsigned long long)f2bf(v.w) << 48);
    *(unsigned long long*)d = pk;
  }
}

// ---------------------------------------------------------------------------
// x [b][c][n] fp32  ->  xT [b*4096+n][c] bf16   (LDS tile transpose)
__global__ __launch_bounds__(256) void transpose_pack(const float* __restrict__ x,
                                                      ushort_t* __restrict__ xT) {
  __shared__ ushort_t tile[64][68];
  int nb = blockIdx.x * 64, cb = blockIdx.y * 64, b = blockIdx.z;
  int tr = threadIdx.x >> 4;            // 0..15
  int tc = (threadIdx.x & 15) * 4;      // 0..60
  const float* src = x + ((size_t)b * C + cb) * NPOS + nb;
#pragma unroll
  for (int it = 0; it < 4; ++it) {
    int c = tr + it * 16;
    float4 v = *(const float4*)(src + (size_t)c * NPOS + tc);
    tile[c][tc + 0] = f2bf(v.x);
    tile[c][tc + 1] = f2bf(v.y);
    tile[c][tc + 2] = f2bf(v.z);
    tile[c][tc + 3] = f2bf(v.w);
  }
  __syncthreads();
  ushort_t* dst = xT + ((size_t)b * NPOS + nb) * C + cb;
#pragma unroll
  for (int it = 0; it < 4; ++it) {
    int n = tr + it * 16;
    unsigned long long pk =
        (unsigned long long)tile[tc + 0][n] |
        ((unsigned long long)tile[tc + 1][n] << 16) |
        ((unsigned long long)tile[tc + 2][n] << 32) |
        ((unsigned long long)tile[tc + 3][n] << 48);
    *(unsigned long long*)(dst + (size_t)n * C + tc) = pk;
  }
}

// ---------------------------------------------------------------------------
// QK GEMM: qk[p][o] = sum_c xT[p][c] * Wq[o][c],  o in [0,512)  (Q pre-scaled)
// wave = 32 p x 64 o. grid (128 p-tiles, 8 o-tiles).
__global__ __launch_bounds__(256) void gemm_qk(const ushort_t* __restrict__ xT,
                                               const ushort_t* __restrict__ Wq,
                                               ushort_t* __restrict__ qk) {
  int w = threadIdx.x >> 6, l = threadIdx.x & 63;
  int lr = l & 15, lg = l >> 4;
  int mbase = blockIdx.x * 128 + w * 32;
  int nbase = blockIdx.y * 64;
  f32x4 acc[2][4] = {};
#pragma unroll
  for (int kk = 0; kk < 8; ++kk) {
    short8 a0 = *(const short8*)(xT + (size_t)(mbase + lr) * C + kk * 32 + lg * 8);
    short8 a1 = *(const short8*)(xT + (size_t)(mbase + 16 + lr) * C + kk * 32 + lg * 8);
#pragma unroll
    for (int t = 0; t < 4; ++t) {
      short8 b = *(const short8*)(Wq + (size_t)(nbase + t * 16 + lr) * C + kk * 32 + lg * 8);
      acc[0][t] = mfma16(a0, b, acc[0][t]);
      acc[1][t] = mfma16(a1, b, acc[1][t]);
    }
  }
#pragma unroll
  for (int qq = 0; qq < 2; ++qq)
#pragma unroll
    for (int t = 0; t < 4; ++t)
#pragma unroll
      for (int i = 0; i < 4; ++i)
        qk[(size_t)(mbase + qq * 16 + lg * 4 + i) * 512 + nbase + t * 16 + lr] =
            f2bf(acc[qq][t][i]);
}

// ---------------------------------------------------------------------------
// V GEMM with swapped roles: vT[b*256 + ov][n] = sum_c Wq[512+ov][c]*xT[p][c]
// Output is V already transposed (d-major). wave = 32 ov x 64 p.
__global__ __launch_bounds__(256) void gemm_v(const ushort_t* __restrict__ xT,
                                              const ushort_t* __restrict__ Wq,
                                              ushort_t* __restrict__ vT) {
  int w = threadIdx.x >> 6, l = threadIdx.x & 63;
  int lr = l & 15, lg = l >> 4;
  int obase = blockIdx.y * 128 + w * 32;       // 0..255 (V channel)
  int pbase = blockIdx.x * 64;
  f32x4 acc[2][4] = {};
#pragma unroll
  for (int kk = 0; kk < 8; ++kk) {
    short8 a0 = *(const short8*)(Wq + (size_t)(512 + obase + lr) * C + kk * 32 + lg * 8);
    short8 a1 = *(const short8*)(Wq + (size_t)(512 + obase + 16 + lr) * C + kk * 32 + lg * 8);
#pragma unroll
    for (int t = 0; t < 4; ++t) {
      short8 b = *(const short8*)(xT + (size_t)(pbase + t * 16 + lr) * C + kk * 32 + lg * 8);
      acc[0][t] = mfma16(a0, b, acc[0][t]);
      acc[1][t] = mfma16(a1, b, acc[1][t]);
    }
  }
#pragma unroll
  for (int qq = 0; qq < 2; ++qq)
#pragma unroll
    for (int i = 0; i < 4; ++i) {
      int ov = obase + qq * 16 + lg * 4 + i;
#pragma unroll
      for (int t = 0; t < 4; ++t) {
        int p = pbase + t * 16 + lr;
        vT[((size_t)((p >> 12) * 256 + ov)) * NPOS + (p & 4095)] = f2bf(acc[qq][t][i]);
      }
    }
}

// ---------------------------------------------------------------------------
// Flash attention — FINAL config (round 12, verified twice: 135.5 us attn /
// 179.6-179.7 us total). Block = 4 waves x 32 q-rows = 128 q. grid
// (32 qtiles, 16 bh) = 512 blocks, 2 blocks/CU (LDS 48 KB), 8 waves/CU.
// Four waves share one staged K/V tile (per-thread staging = 2 b128 loads +
// 2 ds_writes; 1-wave/2-wave variants measured slower: 330/145 us).
// Double-buffered, ONE barrier per iter. Techniques (each A/B-verified):
// key-permuted QK^T (lane's 4 S-values = contiguous keys -> uint2 P-write),
// defer-max (skip rescale while s <= mi+8, per-lane check), per-lane li
// (reduced once at end), v_cvt_pk_bf16_f32 P-pack via __float22bfloat162_rn,
// bare v_exp_f32 softmax (log2e folded into W_q; libm exp2f = +36us),
// XOR-swizzled LDS (conflict-free staging writes + fragment reads).
// NOT kept (measured regressions): setprio (-2%), kt-loop unroll-2 (-25%),
// launch_bounds(,4) single-buffer (VGPR cap -> spill, 5x), single-buffer +
// 2 barriers (+16%: grid of 512 blocks caps occupancy at 2 blocks/CU anyway).
__global__ __launch_bounds__(256, 2) void attn_kernel(const ushort_t* __restrict__ qk,
                                                      const ushort_t* __restrict__ vT,
                                                      ushort_t* __restrict__ ao) {
  __shared__ ushort_t Ks[2][64][64];      // [buf][key][d], swizzled rows (16 KB)
  __shared__ ushort_t Vs[2][64][64];      // [buf][d][key], swizzled rows (16 KB)
  __shared__ ushort_t Pw[4][2048];        // per-wave P [32 q][64 key] (16 KB)

  int tid = threadIdx.x;                  // 0..255
  int w = tid >> 6, l = tid & 63;
  int lr = l & 15, lg = l >> 4;

  int bh = blockIdx.y;
  int qtile = blockIdx.x;                 // 0..31
  int b = bh >> 2, h = bh & 3;
  size_t bbase = (size_t)b * NPOS;
  int qbase = qtile * 128 + w * 32;       // this wave's 32 q-rows

  const ushort_t* qkb = qk + bbase * 512;
  const ushort_t* vTb = vT + ((size_t)(b * 256 + h * DH)) * NPOS;

  // ---- staging setup: thread handles chunks c = tid + j*256, j=0..1 ----
  // chunk c: row = c>>3 (key for K, d for V), 16B slot = c&7.
  const ushort_t* ksrc[2];
  const ushort_t* vsrc[2];
  ushort_t* kdst[2];
  ushort_t* vdst[2];
#pragma unroll
  for (int j = 0; j < 2; ++j) {
    int c = j * 256 + tid;
    int row = c >> 3, slot = c & 7;
    ksrc[j] = qkb + (size_t)row * 512 + 256 + h * DH + slot * 8;   // tile 0
    vsrc[j] = vTb + (size_t)row * NPOS + slot * 8;                 // tile 0
    kdst[j] = &Ks[0][row][((slot * 16) ^ (((row >> 2) & 7) << 4)) >> 1];
    vdst[j] = &Vs[0][row][((slot * 16) ^ ((row & 7) << 4)) >> 1];
  }
  short8 gk[2], gv[2];
#pragma unroll
  for (int j = 0; j < 2; ++j) {           // prologue: load tile 0
    gk[j] = *(const short8*)ksrc[j];
    gv[j] = *(const short8*)vsrc[j];
  }

  // ---- Q fragments hoisted (scale + log2e pre-folded into W_q) ----
  short8 aq[2][2];
#pragma unroll
  for (int qq = 0; qq < 2; ++qq)
#pragma unroll
    for (int ks = 0; ks < 2; ++ks)
      aq[qq][ks] = *(const short8*)(qkb + (size_t)(qbase + qq * 16 + lr) * 512 +
                                    h * DH + ks * 32 + lg * 8);

  f32x4 o[2][4] = {};
  float mi[2][4] = {{-1e30f, -1e30f, -1e30f, -1e30f}, {-1e30f, -1e30f, -1e30f, -1e30f}};
  float li[2][4] = {};                    // per-lane partial row sums

  for (int kt = 0; kt < 64; ++kt) {
    int buf = kt & 1;
    // ---- write phase: regs (tile kt) -> LDS buf ----
#pragma unroll
    for (int j = 0; j < 2; ++j) {
      *(short8*)(kdst[j] + buf * 4096) = gk[j];
      *(short8*)(vdst[j] + buf * 4096) = gv[j];
    }
    __syncthreads();

    // ---- issue next tile's loads (latency hides under compute) ----
    if (kt < 63) {
#pragma unroll
      for (int j = 0; j < 2; ++j) {
        ksrc[j] += 64 * 512;
        vsrc[j] += 64;
        gk[j] = *(const short8*)ksrc[j];
        gv[j] = *(const short8*)vsrc[j];
      }
    }

    // ---- S' = Q K^T (log2e-scaled; keys permuted: frag t col lr = key lr*4+t)
    f32x4 s[2][4] = {};
#pragma unroll
    for (int ks = 0; ks < 2; ++ks) {
      short8 bk[4];
#pragma unroll
      for (int t = 0; t < 4; ++t) {
        int row = lr * 4 + t;             // row>>2 == lr
        int colb = (ks * 64 + lg * 16) ^ ((lr & 7) << 4);
        bk[t] = *(const short8*)&Ks[buf][row][colb >> 1];
      }
#pragma unroll
      for (int qq = 0; qq < 2; ++qq)
#pragma unroll
        for (int t = 0; t < 4; ++t)
          s[qq][t] = mfma16(aq[qq][ks], bk[t], s[qq][t]);
    }

    // ---- online softmax (exp2 domain) with defer-max ----
    float m4[2][4];
    bool bad = false;
#pragma unroll
    for (int qq = 0; qq < 2; ++qq)
#pragma unroll
      for (int i = 0; i < 4; ++i) {
        m4[qq][i] = fmaxf(fmaxf(s[qq][0][i], s[qq][1][i]),
                          fmaxf(s[qq][2][i], s[qq][3][i]));
        bad = bad || (m4[qq][i] > mi[qq][i] + 8.0f);
      }

    if (__any(bad)) {
      // slow path: full online-softmax rescale (rare after first tiles)
#pragma unroll
      for (int qq = 0; qq < 2; ++qq)
#pragma unroll
        for (int i = 0; i < 4; ++i) {
          float mx = m4[qq][i];
#pragma unroll
          for (int msk = 1; msk <= 8; msk <<= 1) mx = fmaxf(mx, __shfl_xor(mx, msk, 64));
          float mnew = fmaxf(mi[qq][i], mx);
          float corr = fast_exp2(mi[qq][i] - mnew);
          float p0 = fast_exp2(s[qq][0][i] - mnew);
          float p1 = fast_exp2(s[qq][1][i] - mnew);
          float p2 = fast_exp2(s[qq][2][i] - mnew);
          float p3 = fast_exp2(s[qq][3][i] - mnew);
          li[qq][i] = li[qq][i] * corr + ((p0 + p1) + (p2 + p3));
          mi[qq][i] = mnew;
#pragma unroll
          for (int t = 0; t < 4; ++t) o[qq][t][i] *= corr;
          int r = qq * 16 + lg * 4 + i;
          uint2 pr;
          pr.x = pack_bf16x2(p0, p1);
          pr.y = pack_bf16x2(p2, p3);
          *(uint2*)&Pw[w][r * 64 + ((lr * 4) ^ ((r & 7) << 3))] = pr;
        }
    } else {
      // fast path: stale max, no cross-lane ops, no rescale
#pragma unroll
      for (int qq = 0; qq < 2; ++qq)
#pragma unroll
        for (int i = 0; i < 4; ++i) {
          float m = mi[qq][i];
          float p0 = fast_exp2(s[qq][0][i] - m);
          float p1 = fast_exp2(s[qq][1][i] - m);
          float p2 = fast_exp2(s[qq][2][i] - m);
          float p3 = fast_exp2(s[qq][3][i] - m);
          li[qq][i] += (p0 + p1) + (p2 + p3);
          int r = qq * 16 + lg * 4 + i;
          uint2 pr;
          pr.x = pack_bf16x2(p0, p1);
          pr.y = pack_bf16x2(p2, p3);
          *(uint2*)&Pw[w][r * 64 + ((lr * 4) ^ ((r & 7) << 3))] = pr;
        }
    }

    // ---- O += P V ----
#pragma unroll
    for (int kk = 0; kk < 2; ++kk) {
      short8 bv[4];
#pragma unroll
      for (int t = 0; t < 4; ++t) {
        int row = t * 16 + lr;
        int colb = (kk * 64 + lg * 16) ^ ((row & 7) << 4);
        bv[t] = *(const short8*)&Vs[buf][row][colb >> 1];
      }
#pragma unroll
      for (int qq = 0; qq < 2; ++qq) {
        int r = qq * 16 + lr;
        short8 ap = *(const short8*)&Pw[w][r * 64 + ((kk * 32 + lg * 8) ^ ((r & 7) << 3))];
#pragma unroll
        for (int t = 0; t < 4; ++t) o[qq][t] = mfma16(ap, bv[t], o[qq][t]);
      }
    }
    // no trailing barrier: double-buffer + the single post-write barrier
    // orders all cross-wave hazards (writes at kt+1 target the other buffer).
  }

  // ---- reduce per-lane li across the 16 lr-lanes of each row group ----
#pragma unroll
  for (int qq = 0; qq < 2; ++qq)
#pragma unroll
    for (int i = 0; i < 4; ++i) {
      float rs = li[qq][i];
#pragma unroll
      for (int msk = 1; msk <= 8; msk <<= 1) rs += __shfl_xor(rs, msk, 64);
      li[qq][i] = rs;
    }

  // ---- epilogue: ao[p][h*64+d] = O/li ----
#pragma unroll
  for (int qq = 0; qq < 2; ++qq)
#pragma unroll
    for (int i = 0; i < 4; ++i) {
      float inv = 1.0f / li[qq][i];
      size_t p = bbase + qbase + qq * 16 + lg * 4 + i;
#pragma unroll
      for (int t = 0; t < 4; ++t)
        ao[p * C + h * DH + t * 16 + lr] = f2bf(o[qq][t][i] * inv);
    }
}

// ---------------------------------------------------------------------------
// Proj GEMM: out[b][o][n] = sum_c Wp[o][c]*ao[p][c] + bias[o]
// wave = 32 o x 64 p. grid (256 p-tiles, 2 o-tiles). fp32 stores to [o][n].
__global__ __launch_bounds__(256) void gemm_proj(const ushort_t* __restrict__ ao,
                                                 const ushort_t* __restrict__ Wp,
                                                 const float* __restrict__ bias,
                                                 float* __restrict__ out) {
  int w = threadIdx.x >> 6, l = threadIdx.x & 63;
  int lr = l & 15, lg = l >> 4;
  int obase = blockIdx.y * 128 + w * 32;
  int pbase = blockIdx.x * 64;
  f32x4 acc[2][4] = {};
#pragma unroll
  for (int kk = 0; kk < 8; ++kk) {
    short8 a0 = *(const short8*)(Wp + (size_t)(obase + lr) * C + kk * 32 + lg * 8);
    short8 a1 = *(const short8*)(Wp + (size_t)(obase + 16 + lr) * C + kk * 32 + lg * 8);
#pragma unroll
    for (int t = 0; t < 4; ++t) {
      short8 b = *(const short8*)(ao + (size_t)(pbase + t * 16 + lr) * C + kk * 32 + lg * 8);
      acc[0][t] = mfma16(a0, b, acc[0][t]);
      acc[1][t] = mfma16(a1, b, acc[1][t]);
    }
  }
#pragma unroll
  for (int qq = 0; qq < 2; ++qq)
#pragma unroll
    for (int i = 0; i < 4; ++i) {
      int oc = obase + qq * 16 + lg * 4 + i;
      float bv = bias[oc];
#pragma unroll
      for (int t = 0; t < 4; ++t) {
        int p = pbase + t * 16 + lr;
        out[((size_t)(p >> 12) * C + oc) * NPOS + (p & 4095)] = acc[qq][t][i] + bv;
      }
    }
}

// ---------------------------------------------------------------------------
extern "C" void kernel_launch(void* const* d_in, const int* in_sizes, int n_in,
                              void* d_out, int out_size, void* d_ws, size_t ws_size,
                              hipStream_t stream) {
  const float* x      = (const float*)d_in[0];
  const float* w_qkv  = (const float*)d_in[1];
  const float* w_proj = (const float*)d_in[2];
  const float* b_proj = (const float*)d_in[3];
  float* out = (float*)d_out;

  char* ws = (char*)d_ws;
  ushort_t* xT  = (ushort_t*)(ws);                 // 16384*256*2  =  8,388,608
  ushort_t* wqb = (ushort_t*)(ws + 8388608);       // 768*256*2    =    393,216
  ushort_t* wpb = (ushort_t*)(ws + 8781824);       // 256*256*2    =    131,072
  ushort_t* qk  = (ushort_t*)(ws + 8912896);       // 16384*512*2  = 16,777,216
  ushort_t* vT  = (ushort_t*)(ws + 25690112);      // 4*256*4096*2 =  8,388,608
  ushort_t* ao  = (ushort_t*)(ws + 34078720);      // 16384*256*2  =  8,388,608
                                                   // total 42,467,328 bytes

  pack_w<<<256, 256, 0, stream>>>(w_qkv, w_proj, wqb, wpb);
  transpose_pack<<<dim3(64, 4, 4), 256, 0, stream>>>(x, xT);
  gemm_qk<<<dim3(128, 8), 256, 0, stream>>>(xT, wqb, qk);
  gemm_v<<<dim3(256, 2), 256, 0, stream>>>(xT, wqb, vT);
  attn_kernel<<<dim3(32, 16), 256, 0, stream>>>(qk, vT, ao);
  gemm_proj<<<dim3(256, 2), 256, 0, stream>>>(ao, wpb, b_proj, out);
}

// Round 18
// 170.138 us; speedup vs baseline: 1.1866x; 1.0555x over previous
//
#include <hip/hip_runtime.h>
#include <hip/hip_bf16.h>

// Problem constants (B=4, C=256, H=W=64, heads=4)
#define NPOS   4096          // H*W
#define TOTP   16384         // B*NPOS
#define C      256
#define DH     64

typedef unsigned short ushort_t;
typedef __attribute__((ext_vector_type(8))) short short8;   // 8 bf16 (4 VGPRs) MFMA A/B frag
typedef __attribute__((ext_vector_type(4))) float f32x4;    // MFMA C/D frag

__device__ __forceinline__ f32x4 mfma16(short8 a, short8 b, f32x4 c) {
  return __builtin_amdgcn_mfma_f32_16x16x32_bf16(a, b, c, 0, 0, 0);
}

// fp32 -> bf16 bits, round-to-nearest-even (inputs finite)
__device__ __forceinline__ ushort_t f2bf(float f) {
  union { float f; unsigned int u; } v;
  v.f = f;
  unsigned int r = v.u + 0x7FFFu + ((v.u >> 16) & 1u);
  return (ushort_t)(r >> 16);
}

// pack two fp32 -> u32 of 2x bf16 (RNE) via the official conversion intrinsic;
// hipcc lowers the pair to v_cvt_pk_bf16_f32 (1 op vs ~12 for bit-twiddle).
__device__ __forceinline__ unsigned int pack_bf16x2(float lo, float hi) {
  __hip_bfloat162 h = __float22bfloat162_rn(float2{lo, hi});
  union { __hip_bfloat162 h; unsigned int u; } v;
  v.h = h;
  return v.u;
}

// raw v_exp_f32: D = 2^S0, single trans op. Inputs bounded <= +8 by defer-max;
// large-negative inputs flush to 0 (desired for softmax).
__device__ __forceinline__ float fast_exp2(float x) {
  float r;
  asm("v_exp_f32 %0, %1" : "=v"(r) : "v"(x));
  return r;
}

// ---------------------------------------------------------------------------
// FUSED prep kernel: blocks [0,256) = pack_w, blocks [256,1280) = transpose.
// Bodies byte-identical to the verified standalone kernels; only blockIdx
// decoding differs. Saves one launch gap + pack hides under transpose.
__global__ __launch_bounds__(256) void prep_kernel(const float* __restrict__ x,
                                                   const float* __restrict__ wq,
                                                   const float* __restrict__ wp,
                                                   ushort_t* __restrict__ xT,
                                                   ushort_t* __restrict__ wqb,
                                                   ushort_t* __restrict__ wpb) {
  __shared__ ushort_t tile[64][68];
  int bid = blockIdx.x;
  if (bid < 256) {
    // ---- pack_w: Q rows (o<256) get 0.125*log2(e) folded in ----
    int idx = bid * 256 + threadIdx.x;
    if (idx < 49152) {                     // w_qkv: 768*256 = 196608 = 49152*4
      float4 v = *(const float4*)(wq + (size_t)idx * 4);
      float sc = (idx * 4 < 65536) ? 0.18033688f : 1.0f;
      ushort_t* d = wqb + (size_t)idx * 4;
      unsigned long long pk =
          (unsigned long long)f2bf(v.x * sc) |
          ((unsigned long long)f2bf(v.y * sc) << 16) |
          ((unsigned long long)f2bf(v.z * sc) << 32) |
          ((unsigned long long)f2bf(v.w * sc) << 48);
      *(unsigned long long*)d = pk;
    } else {                               // w_proj: 256*256 = 65536 = 16384*4
      int j = idx - 49152;
      float4 v = *(const float4*)(wp + (size_t)j * 4);
      ushort_t* d = wpb + (size_t)j * 4;
      unsigned long long pk =
          (unsigned long long)f2bf(v.x) |
          ((unsigned long long)f2bf(v.y) << 16) |
          ((unsigned long long)f2bf(v.z) << 32) |
          ((unsigned long long)f2bf(v.w) << 48);
      *(unsigned long long*)d = pk;
    }
  } else {
    // ---- transpose_pack: x [b][c][n] fp32 -> xT [b*4096+n][c] bf16 ----
    int blk = bid - 256;                   // 0..1023 = (64 nb, 4 cb, 4 b)
    int nb = (blk & 63) * 64, cb = ((blk >> 6) & 3) * 64, b = blk >> 8;
    int tr = threadIdx.x >> 4;             // 0..15
    int tc = (threadIdx.x & 15) * 4;       // 0..60
    const float* src = x + ((size_t)b * C + cb) * NPOS + nb;
#pragma unroll
    for (int it = 0; it < 4; ++it) {
      int c = tr + it * 16;
      float4 v = *(const float4*)(src + (size_t)c * NPOS + tc);
      tile[c][tc + 0] = f2bf(v.x);
      tile[c][tc + 1] = f2bf(v.y);
      tile[c][tc + 2] = f2bf(v.z);
      tile[c][tc + 3] = f2bf(v.w);
    }
    __syncthreads();
    ushort_t* dst = xT + ((size_t)b * NPOS + nb) * C + cb;
#pragma unroll
    for (int it = 0; it < 4; ++it) {
      int n = tr + it * 16;
      unsigned long long pk =
          (unsigned long long)tile[tc + 0][n] |
          ((unsigned long long)tile[tc + 1][n] << 16) |
          ((unsigned long long)tile[tc + 2][n] << 32) |
          ((unsigned long long)tile[tc + 3][n] << 48);
      *(unsigned long long*)(dst + (size_t)n * C + tc) = pk;
    }
  }
}

// ---------------------------------------------------------------------------
// FUSED QKV GEMM: blocks [0,1024) = QK (qk[p][o], o in [0,512), Q pre-scaled),
// blocks [1024,1536) = V with swapped roles (vT[b*256+ov][n], pre-transposed).
// Bodies byte-identical to verified standalone kernels; V blocks fill QK's
// tail instead of waiting for a separate launch.
__global__ __launch_bounds__(256) void gemm_qkv(const ushort_t* __restrict__ xT,
                                                const ushort_t* __restrict__ Wq,
                                                ushort_t* __restrict__ qk,
                                                ushort_t* __restrict__ vT) {
  int bid = blockIdx.x;
  int w = threadIdx.x >> 6, l = threadIdx.x & 63;
  int lr = l & 15, lg = l >> 4;
  if (bid < 1024) {
    // ---- QK: wave = 32 p x 64 o; (128 p-tiles, 8 o-tiles) ----
    int mbase = (bid & 127) * 128 + w * 32;
    int nbase = (bid >> 7) * 64;
    f32x4 acc[2][4] = {};
#pragma unroll
    for (int kk = 0; kk < 8; ++kk) {
      short8 a0 = *(const short8*)(xT + (size_t)(mbase + lr) * C + kk * 32 + lg * 8);
      short8 a1 = *(const short8*)(xT + (size_t)(mbase + 16 + lr) * C + kk * 32 + lg * 8);
#pragma unroll
      for (int t = 0; t < 4; ++t) {
        short8 b = *(const short8*)(Wq + (size_t)(nbase + t * 16 + lr) * C + kk * 32 + lg * 8);
        acc[0][t] = mfma16(a0, b, acc[0][t]);
        acc[1][t] = mfma16(a1, b, acc[1][t]);
      }
    }
#pragma unroll
    for (int qq = 0; qq < 2; ++qq)
#pragma unroll
      for (int t = 0; t < 4; ++t)
#pragma unroll
        for (int i = 0; i < 4; ++i)
          qk[(size_t)(mbase + qq * 16 + lg * 4 + i) * 512 + nbase + t * 16 + lr] =
              f2bf(acc[qq][t][i]);
  } else {
    // ---- V: wave = 32 ov x 64 p; (256 p-tiles, 2 ov-tiles) ----
    int bid2 = bid - 1024;
    int obase = (bid2 >> 8) * 128 + w * 32;    // 0..255 (V channel)
    int pbase = (bid2 & 255) * 64;
    f32x4 acc[2][4] = {};
#pragma unroll
    for (int kk = 0; kk < 8; ++kk) {
      short8 a0 = *(const short8*)(Wq + (size_t)(512 + obase + lr) * C + kk * 32 + lg * 8);
      short8 a1 = *(const short8*)(Wq + (size_t)(512 + obase + 16 + lr) * C + kk * 32 + lg * 8);
#pragma unroll
      for (int t = 0; t < 4; ++t) {
        short8 b = *(const short8*)(xT + (size_t)(pbase + t * 16 + lr) * C + kk * 32 + lg * 8);
        acc[0][t] = mfma16(a0, b, acc[0][t]);
        acc[1][t] = mfma16(a1, b, acc[1][t]);
      }
    }
#pragma unroll
    for (int qq = 0; qq < 2; ++qq)
#pragma unroll
      for (int i = 0; i < 4; ++i) {
        int ov = obase + qq * 16 + lg * 4 + i;
#pragma unroll
        for (int t = 0; t < 4; ++t) {
          int p = pbase + t * 16 + lr;
          vT[((size_t)((p >> 12) * 256 + ov)) * NPOS + (p & 4095)] = f2bf(acc[qq][t][i]);
        }
      }
  }
}

// ---------------------------------------------------------------------------
// Flash attention — FINAL config (round 12, verified 3x: 135.0-135.5 us attn).
// Block = 4 waves x 32 q-rows = 128 q. grid (32 qtiles, 16 bh) = 512 blocks,
// 2 blocks/CU (LDS 48 KB), 8 waves/CU. Four waves share one staged K/V tile
// (per-thread staging = 2 b128 loads + 2 ds_writes; 1-wave/2-wave variants
// measured slower: 330/145 us). Double-buffered, ONE barrier per iter.
// Techniques (each A/B-verified): key-permuted QK^T, defer-max, per-lane li,
// v_cvt_pk_bf16_f32 P-pack, bare v_exp_f32 softmax (log2e folded into W_q),
// XOR-swizzled LDS. NOT kept (measured regressions): setprio (-2%),
// unroll-2 (-25%), launch_bounds(,4) (spill, 5x), single-buffer (+16%).
__global__ __launch_bounds__(256, 2) void attn_kernel(const ushort_t* __restrict__ qk,
                                                      const ushort_t* __restrict__ vT,
                                                      ushort_t* __restrict__ ao) {
  __shared__ ushort_t Ks[2][64][64];      // [buf][key][d], swizzled rows (16 KB)
  __shared__ ushort_t Vs[2][64][64];      // [buf][d][key], swizzled rows (16 KB)
  __shared__ ushort_t Pw[4][2048];        // per-wave P [32 q][64 key] (16 KB)

  int tid = threadIdx.x;                  // 0..255
  int w = tid >> 6, l = tid & 63;
  int lr = l & 15, lg = l >> 4;

  int bh = blockIdx.y;
  int qtile = blockIdx.x;                 // 0..31
  int b = bh >> 2, h = bh & 3;
  size_t bbase = (size_t)b * NPOS;
  int qbase = qtile * 128 + w * 32;       // this wave's 32 q-rows

  const ushort_t* qkb = qk + bbase * 512;
  const ushort_t* vTb = vT + ((size_t)(b * 256 + h * DH)) * NPOS;

  // ---- staging setup: thread handles chunks c = tid + j*256, j=0..1 ----
  // chunk c: row = c>>3 (key for K, d for V), 16B slot = c&7.
  const ushort_t* ksrc[2];
  const ushort_t* vsrc[2];
  ushort_t* kdst[2];
  ushort_t* vdst[2];
#pragma unroll
  for (int j = 0; j < 2; ++j) {
    int c = j * 256 + tid;
    int row = c >> 3, slot = c & 7;
    ksrc[j] = qkb + (size_t)row * 512 + 256 + h * DH + slot * 8;   // tile 0
    vsrc[j] = vTb + (size_t)row * NPOS + slot * 8;                 // tile 0
    kdst[j] = &Ks[0][row][((slot * 16) ^ (((row >> 2) & 7) << 4)) >> 1];
    vdst[j] = &Vs[0][row][((slot * 16) ^ ((row & 7) << 4)) >> 1];
  }
  short8 gk[2], gv[2];
#pragma unroll
  for (int j = 0; j < 2; ++j) {           // prologue: load tile 0
    gk[j] = *(const short8*)ksrc[j];
    gv[j] = *(const short8*)vsrc[j];
  }

  // ---- Q fragments hoisted (scale + log2e pre-folded into W_q) ----
  short8 aq[2][2];
#pragma unroll
  for (int qq = 0; qq < 2; ++qq)
#pragma unroll
    for (int ks = 0; ks < 2; ++ks)
      aq[qq][ks] = *(const short8*)(qkb + (size_t)(qbase + qq * 16 + lr) * 512 +
                                    h * DH + ks * 32 + lg * 8);

  f32x4 o[2][4] = {};
  float mi[2][4] = {{-1e30f, -1e30f, -1e30f, -1e30f}, {-1e30f, -1e30f, -1e30f, -1e30f}};
  float li[2][4] = {};                    // per-lane partial row sums

  for (int kt = 0; kt < 64; ++kt) {
    int buf = kt & 1;
    // ---- write phase: regs (tile kt) -> LDS buf ----
#pragma unroll
    for (int j = 0; j < 2; ++j) {
      *(short8*)(kdst[j] + buf * 4096) = gk[j];
      *(short8*)(vdst[j] + buf * 4096) = gv[j];
    }
    __syncthreads();

    // ---- issue next tile's loads (latency hides under compute) ----
    if (kt < 63) {
#pragma unroll
      for (int j = 0; j < 2; ++j) {
        ksrc[j] += 64 * 512;
        vsrc[j] += 64;
        gk[j] = *(const short8*)ksrc[j];
        gv[j] = *(const short8*)vsrc[j];
      }
    }

    // ---- S' = Q K^T (log2e-scaled; keys permuted: frag t col lr = key lr*4+t)
    f32x4 s[2][4] = {};
#pragma unroll
    for (int ks = 0; ks < 2; ++ks) {
      short8 bk[4];
#pragma unroll
      for (int t = 0; t < 4; ++t) {
        int row = lr * 4 + t;             // row>>2 == lr
        int colb = (ks * 64 + lg * 16) ^ ((lr & 7) << 4);
        bk[t] = *(const short8*)&Ks[buf][row][colb >> 1];
      }
#pragma unroll
      for (int qq = 0; qq < 2; ++qq)
#pragma unroll
        for (int t = 0; t < 4; ++t)
          s[qq][t] = mfma16(aq[qq][ks], bk[t], s[qq][t]);
    }

    // ---- online softmax (exp2 domain) with defer-max ----
    float m4[2][4];
    bool bad = false;
#pragma unroll
    for (int qq = 0; qq < 2; ++qq)
#pragma unroll
      for (int i = 0; i < 4; ++i) {
        m4[qq][i] = fmaxf(fmaxf(s[qq][0][i], s[qq][1][i]),
                          fmaxf(s[qq][2][i], s[qq][3][i]));
        bad = bad || (m4[qq][i] > mi[qq][i] + 8.0f);
      }

    if (__any(bad)) {
      // slow path: full online-softmax rescale (rare after first tiles)
#pragma unroll
      for (int qq = 0; qq < 2; ++qq)
#pragma unroll
        for (int i = 0; i < 4; ++i) {
          float mx = m4[qq][i];
#pragma unroll
          for (int msk = 1; msk <= 8; msk <<= 1) mx = fmaxf(mx, __shfl_xor(mx, msk, 64));
          float mnew = fmaxf(mi[qq][i], mx);
          float corr = fast_exp2(mi[qq][i] - mnew);
          float p0 = fast_exp2(s[qq][0][i] - mnew);
          float p1 = fast_exp2(s[qq][1][i] - mnew);
          float p2 = fast_exp2(s[qq][2][i] - mnew);
          float p3 = fast_exp2(s[qq][3][i] - mnew);
          li[qq][i] = li[qq][i] * corr + ((p0 + p1) + (p2 + p3));
          mi[qq][i] = mnew;
#pragma unroll
          for (int t = 0; t < 4; ++t) o[qq][t][i] *= corr;
          int r = qq * 16 + lg * 4 + i;
          uint2 pr;
          pr.x = pack_bf16x2(p0, p1);
          pr.y = pack_bf16x2(p2, p3);
          *(uint2*)&Pw[w][r * 64 + ((lr * 4) ^ ((r & 7) << 3))] = pr;
        }
    } else {
      // fast path: stale max, no cross-lane ops, no rescale
#pragma unroll
      for (int qq = 0; qq < 2; ++qq)
#pragma unroll
        for (int i = 0; i < 4; ++i) {
          float m = mi[qq][i];
          float p0 = fast_exp2(s[qq][0][i] - m);
          float p1 = fast_exp2(s[qq][1][i] - m);
          float p2 = fast_exp2(s[qq][2][i] - m);
          float p3 = fast_exp2(s[qq][3][i] - m);
          li[qq][i] += (p0 + p1) + (p2 + p3);
          int r = qq * 16 + lg * 4 + i;
          uint2 pr;
          pr.x = pack_bf16x2(p0, p1);
          pr.y = pack_bf16x2(p2, p3);
          *(uint2*)&Pw[w][r * 64 + ((lr * 4) ^ ((r & 7) << 3))] = pr;
        }
    }

    // ---- O += P V ----
#pragma unroll
    for (int kk = 0; kk < 2; ++kk) {
      short8 bv[4];
#pragma unroll
      for (int t = 0; t < 4; ++t) {
        int row = t * 16 + lr;
        int colb = (kk * 64 + lg * 16) ^ ((row & 7) << 4);
        bv[t] = *(const short8*)&Vs[buf][row][colb >> 1];
      }
#pragma unroll
      for (int qq = 0; qq < 2; ++qq) {
        int r = qq * 16 + lr;
        short8 ap = *(const short8*)&Pw[w][r * 64 + ((kk * 32 + lg * 8) ^ ((r & 7) << 3))];
#pragma unroll
        for (int t = 0; t < 4; ++t) o[qq][t] = mfma16(ap, bv[t], o[qq][t]);
      }
    }
    // no trailing barrier: double-buffer + the single post-write barrier
    // orders all cross-wave hazards (writes at kt+1 target the other buffer).
  }

  // ---- reduce per-lane li across the 16 lr-lanes of each row group ----
#pragma unroll
  for (int qq = 0; qq < 2; ++qq)
#pragma unroll
    for (int i = 0; i < 4; ++i) {
      float rs = li[qq][i];
#pragma unroll
      for (int msk = 1; msk <= 8; msk <<= 1) rs += __shfl_xor(rs, msk, 64);
      li[qq][i] = rs;
    }

  // ---- epilogue: ao[p][h*64+d] = O/li ----
#pragma unroll
  for (int qq = 0; qq < 2; ++qq)
#pragma unroll
    for (int i = 0; i < 4; ++i) {
      float inv = 1.0f / li[qq][i];
      size_t p = bbase + qbase + qq * 16 + lg * 4 + i;
#pragma unroll
      for (int t = 0; t < 4; ++t)
        ao[p * C + h * DH + t * 16 + lr] = f2bf(o[qq][t][i] * inv);
    }
}

// ---------------------------------------------------------------------------
// Proj GEMM: out[b][o][n] = sum_c Wp[o][c]*ao[p][c] + bias[o]
// wave = 32 o x 64 p. grid (256 p-tiles, 2 o-tiles). fp32 stores to [o][n].
__global__ __launch_bounds__(256) void gemm_proj(const ushort_t* __restrict__ ao,
                                                 const ushort_t* __restrict__ Wp,
                                                 const float* __restrict__ bias,
                                                 float* __restrict__ out) {
  int w = threadIdx.x >> 6, l = threadIdx.x & 63;
  int lr = l & 15, lg = l >> 4;
  int obase = blockIdx.y * 128 + w * 32;
  int pbase = blockIdx.x * 64;
  f32x4 acc[2][4] = {};
#pragma unroll
  for (int kk = 0; kk < 8; ++kk) {
    short8 a0 = *(const short8*)(Wp + (size_t)(obase + lr) * C + kk * 32 + lg * 8);
    short8 a1 = *(const short8*)(Wp + (size_t)(obase + 16 + lr) * C + kk * 32 + lg * 8);
#pragma unroll
    for (int t = 0; t < 4; ++t) {
      short8 b = *(const short8*)(ao + (size_t)(pbase + t * 16 + lr) * C + kk * 32 + lg * 8);
      acc[0][t] = mfma16(a0, b, acc[0][t]);
      acc[1][t] = mfma16(a1, b, acc[1][t]);
    }
  }
#pragma unroll
  for (int qq = 0; qq < 2; ++qq)
#pragma unroll
    for (int i = 0; i < 4; ++i) {
      int oc = obase + qq * 16 + lg * 4 + i;
      float bv = bias[oc];
#pragma unroll
      for (int t = 0; t < 4; ++t) {
        int p = pbase + t * 16 + lr;
        out[((size_t)(p >> 12) * C + oc) * NPOS + (p & 4095)] = acc[qq][t][i] + bv;
      }
    }
}

// ---------------------------------------------------------------------------
extern "C" void kernel_launch(void* const* d_in, const int* in_sizes, int n_in,
                              void* d_out, int out_size, void* d_ws, size_t ws_size,
                              hipStream_t stream) {
  const float* x      = (const float*)d_in[0];
  const float* w_qkv  = (const float*)d_in[1];
  const float* w_proj = (const float*)d_in[2];
  const float* b_proj = (const float*)d_in[3];
  float* out = (float*)d_out;

  char* ws = (char*)d_ws;
  ushort_t* xT  = (ushort_t*)(ws);                 // 16384*256*2  =  8,388,608
  ushort_t* wqb = (ushort_t*)(ws + 8388608);       // 768*256*2    =    393,216
  ushort_t* wpb = (ushort_t*)(ws + 8781824);       // 256*256*2    =    131,072
  ushort_t* qk  = (ushort_t*)(ws + 8912896);       // 16384*512*2  = 16,777,216
  ushort_t* vT  = (ushort_t*)(ws + 25690112);      // 4*256*4096*2 =  8,388,608
  ushort_t* ao  = (ushort_t*)(ws + 34078720);      // 16384*256*2  =  8,388,608
                                                   // total 42,467,328 bytes

  prep_kernel<<<1280, 256, 0, stream>>>(x, w_qkv, w_proj, xT, wqb, wpb);
  gemm_qkv<<<1536, 256, 0, stream>>>(xT, wqb, qk, vT);
  attn_kernel<<<dim3(32, 16), 256, 0, stream>>>(qk, vT, ao);
  gemm_proj<<<dim3(256, 2), 256, 0, stream>>>(ao, wpb, b_proj, out);
}

// Round 19
// 170.105 us; speedup vs baseline: 1.1868x; 1.0002x over previous
//
#include <hip/hip_runtime.h>
#include <hip/hip_bf16.h>

// Problem constants (B=4, C=256, H=W=64, heads=4)
#define NPOS   4096          // H*W
#define TOTP   16384         // B*NPOS
#define C      256
#define DH     64

typedef unsigned short ushort_t;
typedef __attribute__((ext_vector_type(8))) short short8;   // 8 bf16 (4 VGPRs) MFMA A/B frag
typedef __attribute__((ext_vector_type(4))) float f32x4;    // MFMA C/D frag

__device__ __forceinline__ f32x4 mfma16(short8 a, short8 b, f32x4 c) {
  return __builtin_amdgcn_mfma_f32_16x16x32_bf16(a, b, c, 0, 0, 0);
}

// fp32 -> bf16 bits, round-to-nearest-even (inputs finite)
__device__ __forceinline__ ushort_t f2bf(float f) {
  union { float f; unsigned int u; } v;
  v.f = f;
  unsigned int r = v.u + 0x7FFFu + ((v.u >> 16) & 1u);
  return (ushort_t)(r >> 16);
}

// pack two fp32 -> u32 of 2x bf16 (RNE) via the official conversion intrinsic;
// hipcc lowers the pair to v_cvt_pk_bf16_f32 (1 op vs ~12 for bit-twiddle).
__device__ __forceinline__ unsigned int pack_bf16x2(float lo, float hi) {
  __hip_bfloat162 h = __float22bfloat162_rn(float2{lo, hi});
  union { __hip_bfloat162 h; unsigned int u; } v;
  v.h = h;
  return v.u;
}

// raw v_exp_f32: D = 2^S0, single trans op. Inputs bounded <= +8 by defer-max;
// large-negative inputs flush to 0 (desired for softmax).
__device__ __forceinline__ float fast_exp2(float x) {
  float r;
  asm("v_exp_f32 %0, %1" : "=v"(r) : "v"(x));
  return r;
}

// ---------------------------------------------------------------------------
// FUSED prep kernel: blocks [0,256) = pack_w, blocks [256,1280) = transpose.
// Bodies byte-identical to the verified standalone kernels; only blockIdx
// decoding differs. Saves one launch gap + pack hides under transpose.
__global__ __launch_bounds__(256) void prep_kernel(const float* __restrict__ x,
                                                   const float* __restrict__ wq,
                                                   const float* __restrict__ wp,
                                                   ushort_t* __restrict__ xT,
                                                   ushort_t* __restrict__ wqb,
                                                   ushort_t* __restrict__ wpb) {
  __shared__ ushort_t tile[64][68];
  int bid = blockIdx.x;
  if (bid < 256) {
    // ---- pack_w: Q rows (o<256) get 0.125*log2(e) folded in ----
    int idx = bid * 256 + threadIdx.x;
    if (idx < 49152) {                     // w_qkv: 768*256 = 196608 = 49152*4
      float4 v = *(const float4*)(wq + (size_t)idx * 4);
      float sc = (idx * 4 < 65536) ? 0.18033688f : 1.0f;
      ushort_t* d = wqb + (size_t)idx * 4;
      unsigned long long pk =
          (unsigned long long)f2bf(v.x * sc) |
          ((unsigned long long)f2bf(v.y * sc) << 16) |
          ((unsigned long long)f2bf(v.z * sc) << 32) |
          ((unsigned long long)f2bf(v.w * sc) << 48);
      *(unsigned long long*)d = pk;
    } else {                               // w_proj: 256*256 = 65536 = 16384*4
      int j = idx - 49152;
      float4 v = *(const float4*)(wp + (size_t)j * 4);
      ushort_t* d = wpb + (size_t)j * 4;
      unsigned long long pk =
          (unsigned long long)f2bf(v.x) |
          ((unsigned long long)f2bf(v.y) << 16) |
          ((unsigned long long)f2bf(v.z) << 32) |
          ((unsigned long long)f2bf(v.w) << 48);
      *(unsigned long long*)d = pk;
    }
  } else {
    // ---- transpose_pack: x [b][c][n] fp32 -> xT [b*4096+n][c] bf16 ----
    int blk = bid - 256;                   // 0..1023 = (64 nb, 4 cb, 4 b)
    int nb = (blk & 63) * 64, cb = ((blk >> 6) & 3) * 64, b = blk >> 8;
    int tr = threadIdx.x >> 4;             // 0..15
    int tc = (threadIdx.x & 15) * 4;       // 0..60
    const float* src = x + ((size_t)b * C + cb) * NPOS + nb;
#pragma unroll
    for (int it = 0; it < 4; ++it) {
      int c = tr + it * 16;
      float4 v = *(const float4*)(src + (size_t)c * NPOS + tc);
      tile[c][tc + 0] = f2bf(v.x);
      tile[c][tc + 1] = f2bf(v.y);
      tile[c][tc + 2] = f2bf(v.z);
      tile[c][tc + 3] = f2bf(v.w);
    }
    __syncthreads();
    ushort_t* dst = xT + ((size_t)b * NPOS + nb) * C + cb;
#pragma unroll
    for (int it = 0; it < 4; ++it) {
      int n = tr + it * 16;
      unsigned long long pk =
          (unsigned long long)tile[tc + 0][n] |
          ((unsigned long long)tile[tc + 1][n] << 16) |
          ((unsigned long long)tile[tc + 2][n] << 32) |
          ((unsigned long long)tile[tc + 3][n] << 48);
      *(unsigned long long*)(dst + (size_t)n * C + tc) = pk;
    }
  }
}

// ---------------------------------------------------------------------------
// FUSED QKV GEMM: blocks [0,1024) = QK (qk[p][o], o in [0,512), Q pre-scaled),
// blocks [1024,1536) = V with swapped roles (vT[b*256+ov][n], pre-transposed).
// Bodies byte-identical to verified standalone kernels; V blocks fill QK's
// tail instead of waiting for a separate launch.
__global__ __launch_bounds__(256) void gemm_qkv(const ushort_t* __restrict__ xT,
                                                const ushort_t* __restrict__ Wq,
                                                ushort_t* __restrict__ qk,
                                                ushort_t* __restrict__ vT) {
  int bid = blockIdx.x;
  int w = threadIdx.x >> 6, l = threadIdx.x & 63;
  int lr = l & 15, lg = l >> 4;
  if (bid < 1024) {
    // ---- QK: wave = 32 p x 64 o; (128 p-tiles, 8 o-tiles) ----
    int mbase = (bid & 127) * 128 + w * 32;
    int nbase = (bid >> 7) * 64;
    f32x4 acc[2][4] = {};
#pragma unroll
    for (int kk = 0; kk < 8; ++kk) {
      short8 a0 = *(const short8*)(xT + (size_t)(mbase + lr) * C + kk * 32 + lg * 8);
      short8 a1 = *(const short8*)(xT + (size_t)(mbase + 16 + lr) * C + kk * 32 + lg * 8);
#pragma unroll
      for (int t = 0; t < 4; ++t) {
        short8 b = *(const short8*)(Wq + (size_t)(nbase + t * 16 + lr) * C + kk * 32 + lg * 8);
        acc[0][t] = mfma16(a0, b, acc[0][t]);
        acc[1][t] = mfma16(a1, b, acc[1][t]);
      }
    }
#pragma unroll
    for (int qq = 0; qq < 2; ++qq)
#pragma unroll
      for (int t = 0; t < 4; ++t)
#pragma unroll
        for (int i = 0; i < 4; ++i)
          qk[(size_t)(mbase + qq * 16 + lg * 4 + i) * 512 + nbase + t * 16 + lr] =
              f2bf(acc[qq][t][i]);
  } else {
    // ---- V: wave = 32 ov x 64 p; (256 p-tiles, 2 ov-tiles) ----
    int bid2 = bid - 1024;
    int obase = (bid2 >> 8) * 128 + w * 32;    // 0..255 (V channel)
    int pbase = (bid2 & 255) * 64;
    f32x4 acc[2][4] = {};
#pragma unroll
    for (int kk = 0; kk < 8; ++kk) {
      short8 a0 = *(const short8*)(Wq + (size_t)(512 + obase + lr) * C + kk * 32 + lg * 8);
      short8 a1 = *(const short8*)(Wq + (size_t)(512 + obase + 16 + lr) * C + kk * 32 + lg * 8);
#pragma unroll
      for (int t = 0; t < 4; ++t) {
        short8 b = *(const short8*)(xT + (size_t)(pbase + t * 16 + lr) * C + kk * 32 + lg * 8);
        acc[0][t] = mfma16(a0, b, acc[0][t]);
        acc[1][t] = mfma16(a1, b, acc[1][t]);
      }
    }
#pragma unroll
    for (int qq = 0; qq < 2; ++qq)
#pragma unroll
      for (int i = 0; i < 4; ++i) {
        int ov = obase + qq * 16 + lg * 4 + i;
#pragma unroll
        for (int t = 0; t < 4; ++t) {
          int p = pbase + t * 16 + lr;
          vT[((size_t)((p >> 12) * 256 + ov)) * NPOS + (p & 4095)] = f2bf(acc[qq][t][i]);
        }
      }
  }
}

// ---------------------------------------------------------------------------
// Flash attention — FINAL config (round 12, verified 3x: 135.0-135.5 us attn).
// Block = 4 waves x 32 q-rows = 128 q. grid (32 qtiles, 16 bh) = 512 blocks,
// 2 blocks/CU (LDS 48 KB), 8 waves/CU. Four waves share one staged K/V tile
// (per-thread staging = 2 b128 loads + 2 ds_writes; 1-wave/2-wave variants
// measured slower: 330/145 us). Double-buffered, ONE barrier per iter.
// Techniques (each A/B-verified): key-permuted QK^T, defer-max, per-lane li,
// v_cvt_pk_bf16_f32 P-pack, bare v_exp_f32 softmax (log2e folded into W_q),
// XOR-swizzled LDS. NOT kept (measured regressions): setprio (-2%),
// unroll-2 (-25%), launch_bounds(,4) (spill, 5x), single-buffer (+16%).
__global__ __launch_bounds__(256, 2) void attn_kernel(const ushort_t* __restrict__ qk,
                                                      const ushort_t* __restrict__ vT,
                                                      ushort_t* __restrict__ ao) {
  __shared__ ushort_t Ks[2][64][64];      // [buf][key][d], swizzled rows (16 KB)
  __shared__ ushort_t Vs[2][64][64];      // [buf][d][key], swizzled rows (16 KB)
  __shared__ ushort_t Pw[4][2048];        // per-wave P [32 q][64 key] (16 KB)

  int tid = threadIdx.x;                  // 0..255
  int w = tid >> 6, l = tid & 63;
  int lr = l & 15, lg = l >> 4;

  int bh = blockIdx.y;
  int qtile = blockIdx.x;                 // 0..31
  int b = bh >> 2, h = bh & 3;
  size_t bbase = (size_t)b * NPOS;
  int qbase = qtile * 128 + w * 32;       // this wave's 32 q-rows

  const ushort_t* qkb = qk + bbase * 512;
  const ushort_t* vTb = vT + ((size_t)(b * 256 + h * DH)) * NPOS;

  // ---- staging setup: thread handles chunks c = tid + j*256, j=0..1 ----
  // chunk c: row = c>>3 (key for K, d for V), 16B slot = c&7.
  const ushort_t* ksrc[2];
  const ushort_t* vsrc[2];
  ushort_t* kdst[2];
  ushort_t* vdst[2];
#pragma unroll
  for (int j = 0; j < 2; ++j) {
    int c = j * 256 + tid;
    int row = c >> 3, slot = c & 7;
    ksrc[j] = qkb + (size_t)row * 512 + 256 + h * DH + slot * 8;   // tile 0
    vsrc[j] = vTb + (size_t)row * NPOS + slot * 8;                 // tile 0
    kdst[j] = &Ks[0][row][((slot * 16) ^ (((row >> 2) & 7) << 4)) >> 1];
    vdst[j] = &Vs[0][row][((slot * 16) ^ ((row & 7) << 4)) >> 1];
  }
  short8 gk[2], gv[2];
#pragma unroll
  for (int j = 0; j < 2; ++j) {           // prologue: load tile 0
    gk[j] = *(const short8*)ksrc[j];
    gv[j] = *(const short8*)vsrc[j];
  }

  // ---- Q fragments hoisted (scale + log2e pre-folded into W_q) ----
  short8 aq[2][2];
#pragma unroll
  for (int qq = 0; qq < 2; ++qq)
#pragma unroll
    for (int ks = 0; ks < 2; ++ks)
      aq[qq][ks] = *(const short8*)(qkb + (size_t)(qbase + qq * 16 + lr) * 512 +
                                    h * DH + ks * 32 + lg * 8);

  f32x4 o[2][4] = {};
  float mi[2][4] = {{-1e30f, -1e30f, -1e30f, -1e30f}, {-1e30f, -1e30f, -1e30f, -1e30f}};
  float li[2][4] = {};                    // per-lane partial row sums

  for (int kt = 0; kt < 64; ++kt) {
    int buf = kt & 1;
    // ---- write phase: regs (tile kt) -> LDS buf ----
#pragma unroll
    for (int j = 0; j < 2; ++j) {
      *(short8*)(kdst[j] + buf * 4096) = gk[j];
      *(short8*)(vdst[j] + buf * 4096) = gv[j];
    }
    __syncthreads();

    // ---- issue next tile's loads (latency hides under compute) ----
    if (kt < 63) {
#pragma unroll
      for (int j = 0; j < 2; ++j) {
        ksrc[j] += 64 * 512;
        vsrc[j] += 64;
        gk[j] = *(const short8*)ksrc[j];
        gv[j] = *(const short8*)vsrc[j];
      }
    }

    // ---- S' = Q K^T (log2e-scaled; keys permuted: frag t col lr = key lr*4+t)
    f32x4 s[2][4] = {};
#pragma unroll
    for (int ks = 0; ks < 2; ++ks) {
      short8 bk[4];
#pragma unroll
      for (int t = 0; t < 4; ++t) {
        int row = lr * 4 + t;             // row>>2 == lr
        int colb = (ks * 64 + lg * 16) ^ ((lr & 7) << 4);
        bk[t] = *(const short8*)&Ks[buf][row][colb >> 1];
      }
#pragma unroll
      for (int qq = 0; qq < 2; ++qq)
#pragma unroll
        for (int t = 0; t < 4; ++t)
          s[qq][t] = mfma16(aq[qq][ks], bk[t], s[qq][t]);
    }

    // ---- online softmax (exp2 domain) with defer-max ----
    float m4[2][4];
    bool bad = false;
#pragma unroll
    for (int qq = 0; qq < 2; ++qq)
#pragma unroll
      for (int i = 0; i < 4; ++i) {
        m4[qq][i] = fmaxf(fmaxf(s[qq][0][i], s[qq][1][i]),
                          fmaxf(s[qq][2][i], s[qq][3][i]));
        bad = bad || (m4[qq][i] > mi[qq][i] + 8.0f);
      }

    if (__any(bad)) {
      // slow path: full online-softmax rescale (rare after first tiles)
#pragma unroll
      for (int qq = 0; qq < 2; ++qq)
#pragma unroll
        for (int i = 0; i < 4; ++i) {
          float mx = m4[qq][i];
#pragma unroll
          for (int msk = 1; msk <= 8; msk <<= 1) mx = fmaxf(mx, __shfl_xor(mx, msk, 64));
          float mnew = fmaxf(mi[qq][i], mx);
          float corr = fast_exp2(mi[qq][i] - mnew);
          float p0 = fast_exp2(s[qq][0][i] - mnew);
          float p1 = fast_exp2(s[qq][1][i] - mnew);
          float p2 = fast_exp2(s[qq][2][i] - mnew);
          float p3 = fast_exp2(s[qq][3][i] - mnew);
          li[qq][i] = li[qq][i] * corr + ((p0 + p1) + (p2 + p3));
          mi[qq][i] = mnew;
#pragma unroll
          for (int t = 0; t < 4; ++t) o[qq][t][i] *= corr;
          int r = qq * 16 + lg * 4 + i;
          uint2 pr;
          pr.x = pack_bf16x2(p0, p1);
          pr.y = pack_bf16x2(p2, p3);
          *(uint2*)&Pw[w][r * 64 + ((lr * 4) ^ ((r & 7) << 3))] = pr;
        }
    } else {
      // fast path: stale max, no cross-lane ops, no rescale
#pragma unroll
      for (int qq = 0; qq < 2; ++qq)
#pragma unroll
        for (int i = 0; i < 4; ++i) {
          float m = mi[qq][i];
          float p0 = fast_exp2(s[qq][0][i] - m);
          float p1 = fast_exp2(s[qq][1][i] - m);
          float p2 = fast_exp2(s[qq][2][i] - m);
          float p3 = fast_exp2(s[qq][3][i] - m);
          li[qq][i] += (p0 + p1) + (p2 + p3);
          int r = qq * 16 + lg * 4 + i;
          uint2 pr;
          pr.x = pack_bf16x2(p0, p1);
          pr.y = pack_bf16x2(p2, p3);
          *(uint2*)&Pw[w][r * 64 + ((lr * 4) ^ ((r & 7) << 3))] = pr;
        }
    }

    // ---- O += P V ----
#pragma unroll
    for (int kk = 0; kk < 2; ++kk) {
      short8 bv[4];
#pragma unroll
      for (int t = 0; t < 4; ++t) {
        int row = t * 16 + lr;
        int colb = (kk * 64 + lg * 16) ^ ((row & 7) << 4);
        bv[t] = *(const short8*)&Vs[buf][row][colb >> 1];
      }
#pragma unroll
      for (int qq = 0; qq < 2; ++qq) {
        int r = qq * 16 + lr;
        short8 ap = *(const short8*)&Pw[w][r * 64 + ((kk * 32 + lg * 8) ^ ((r & 7) << 3))];
#pragma unroll
        for (int t = 0; t < 4; ++t) o[qq][t] = mfma16(ap, bv[t], o[qq][t]);
      }
    }
    // no trailing barrier: double-buffer + the single post-write barrier
    // orders all cross-wave hazards (writes at kt+1 target the other buffer).
  }

  // ---- reduce per-lane li across the 16 lr-lanes of each row group ----
#pragma unroll
  for (int qq = 0; qq < 2; ++qq)
#pragma unroll
    for (int i = 0; i < 4; ++i) {
      float rs = li[qq][i];
#pragma unroll
      for (int msk = 1; msk <= 8; msk <<= 1) rs += __shfl_xor(rs, msk, 64);
      li[qq][i] = rs;
    }

  // ---- epilogue: ao[p][h*64+d] = O/li ----
#pragma unroll
  for (int qq = 0; qq < 2; ++qq)
#pragma unroll
    for (int i = 0; i < 4; ++i) {
      float inv = 1.0f / li[qq][i];
      size_t p = bbase + qbase + qq * 16 + lg * 4 + i;
#pragma unroll
      for (int t = 0; t < 4; ++t)
        ao[p * C + h * DH + t * 16 + lr] = f2bf(o[qq][t][i] * inv);
    }
}

// ---------------------------------------------------------------------------
// Proj GEMM: out[b][o][n] = sum_c Wp[o][c]*ao[p][c] + bias[o]
// wave = 32 o x 64 p. grid (256 p-tiles, 2 o-tiles). fp32 stores to [o][n].
__global__ __launch_bounds__(256) void gemm_proj(const ushort_t* __restrict__ ao,
                                                 const ushort_t* __restrict__ Wp,
                                                 const float* __restrict__ bias,
                                                 float* __restrict__ out) {
  int w = threadIdx.x >> 6, l = threadIdx.x & 63;
  int lr = l & 15, lg = l >> 4;
  int obase = blockIdx.y * 128 + w * 32;
  int pbase = blockIdx.x * 64;
  f32x4 acc[2][4] = {};
#pragma unroll
  for (int kk = 0; kk < 8; ++kk) {
    short8 a0 = *(const short8*)(Wp + (size_t)(obase + lr) * C + kk * 32 + lg * 8);
    short8 a1 = *(const short8*)(Wp + (size_t)(obase + 16 + lr) * C + kk * 32 + lg * 8);
#pragma unroll
    for (int t = 0; t < 4; ++t) {
      short8 b = *(const short8*)(ao + (size_t)(pbase + t * 16 + lr) * C + kk * 32 + lg * 8);
      acc[0][t] = mfma16(a0, b, acc[0][t]);
      acc[1][t] = mfma16(a1, b, acc[1][t]);
    }
  }
#pragma unroll
  for (int qq = 0; qq < 2; ++qq)
#pragma unroll
    for (int i = 0; i < 4; ++i) {
      int oc = obase + qq * 16 + lg * 4 + i;
      float bv = bias[oc];
#pragma unroll
      for (int t = 0; t < 4; ++t) {
        int p = pbase + t * 16 + lr;
        out[((size_t)(p >> 12) * C + oc) * NPOS + (p & 4095)] = acc[qq][t][i] + bv;
      }
    }
}

// ---------------------------------------------------------------------------
extern "C" void kernel_launch(void* const* d_in, const int* in_sizes, int n_in,
                              void* d_out, int out_size, void* d_ws, size_t ws_size,
                              hipStream_t stream) {
  const float* x      = (const float*)d_in[0];
  const float* w_qkv  = (const float*)d_in[1];
  const float* w_proj = (const float*)d_in[2];
  const float* b_proj = (const float*)d_in[3];
  float* out = (float*)d_out;

  char* ws = (char*)d_ws;
  ushort_t* xT  = (ushort_t*)(ws);                 // 16384*256*2  =  8,388,608
  ushort_t* wqb = (ushort_t*)(ws + 8388608);       // 768*256*2    =    393,216
  ushort_t* wpb = (ushort_t*)(ws + 8781824);       // 256*256*2    =    131,072
  ushort_t* qk  = (ushort_t*)(ws + 8912896);       // 16384*512*2  = 16,777,216
  ushort_t* vT  = (ushort_t*)(ws + 25690112);      // 4*256*4096*2 =  8,388,608
  ushort_t* ao  = (ushort_t*)(ws + 34078720);      // 16384*256*2  =  8,388,608
                                                   // total 42,467,328 bytes

  prep_kernel<<<1280, 256, 0, stream>>>(x, w_qkv, w_proj, xT, wqb, wpb);
  gemm_qkv<<<1536, 256, 0, stream>>>(xT, wqb, qk, vT);
  attn_kernel<<<dim3(32, 16), 256, 0, stream>>>(qk, vT, ao);
  gemm_proj<<<dim3(256, 2), 256, 0, stream>>>(ao, wpb, b_proj, out);
}